// Round 6
// baseline (154.530 us; speedup 1.0000x reference)
//
#include <hip/hip_runtime.h>
#include <math.h>

typedef _Float16 f16x8 __attribute__((ext_vector_type(8)));
typedef float    f32x4 __attribute__((ext_vector_type(4)));

constexpr int kB  = 4;
constexpr int kN  = 512;
constexpr int kE  = 512;
constexpr int kH  = 8;
constexpr int kH2 = 16;
constexpr int kC  = 64;
constexpr int kDV = 64;
constexpr float kLamInit = 0.2f;

// ---- prep: f32->f16 for x, v_w, out_w; block 1536 computes lambda ----------
__global__ __launch_bounds__(256) void prep_kernel(
    const float* __restrict__ x, const float* __restrict__ vw,
    const float* __restrict__ ow,
    const float* __restrict__ lq1, const float* __restrict__ lk1,
    const float* __restrict__ lq2, const float* __restrict__ lk2,
    _Float16* __restrict__ x16, _Float16* __restrict__ w16v,
    _Float16* __restrict__ w16o, float* __restrict__ lam_out) {
  const int bid = blockIdx.x;
  if (bid < 1536) {
    const float* src; _Float16* dst; int base;
    if (bid < 1024)      { src = x;  dst = x16;  base = bid; }
    else if (bid < 1280) { src = vw; dst = w16v; base = bid - 1024; }
    else                 { src = ow; dst = w16o; base = bid - 1280; }
    const int i = base * 256 + threadIdx.x;
    const float4 v = ((const float4*)src)[i];
    union { _Float16 h[4]; uint2 u2; } P;
    P.h[0]=(_Float16)v.x; P.h[1]=(_Float16)v.y;
    P.h[2]=(_Float16)v.z; P.h[3]=(_Float16)v.w;
    *(uint2*)(dst + i * 4) = P.u2;
  } else if (threadIdx.x < 64) {
    float s1 = 0.f, s2 = 0.f;
    for (int i = threadIdx.x; i < kE; i += 64) { s1 += lq1[i]*lk1[i]; s2 += lq2[i]*lk2[i]; }
    #pragma unroll
    for (int o = 32; o; o >>= 1) { s1 += __shfl_xor(s1, o); s2 += __shfl_xor(s2, o); }
    if (threadIdx.x == 0) lam_out[0] = expf(s1) - expf(s2) + kLamInit;
  }
}

// ---- hgemm: C[M,F] = A16[M,K] x W16[F,K]^T (normal layout, f32 out) --------
__global__ __launch_bounds__(256) void hgemm16f(const _Float16* __restrict__ A16,
                                                const _Float16* __restrict__ W16,
                                                float* __restrict__ C,
                                                int M, int F, int K) {
  const int tid = threadIdx.x, lane = tid & 63, wv = tid >> 6;
  const int l15 = lane & 15, l4 = lane >> 4;
  const int m0 = blockIdx.y * 64 + wv * 16;
  const int f0 = blockIdx.x * 64;
  f32x4 acc[4] = {{0,0,0,0},{0,0,0,0},{0,0,0,0},{0,0,0,0}};
  const _Float16* Ap = A16 + (size_t)(m0 + l15) * K + l4 * 8;
  const _Float16* Wp = W16 + (size_t)(f0 + l15) * K + l4 * 8;
  for (int k0 = 0; k0 < K; k0 += 32) {
    const f16x8 af = *(const f16x8*)(Ap + k0);
    #pragma unroll
    for (int t = 0; t < 4; ++t) {
      const f16x8 bf = *(const f16x8*)(Wp + (size_t)t * 16 * K + k0);
      acc[t] = __builtin_amdgcn_mfma_f32_16x16x32_f16(af, bf, acc[t], 0, 0, 0);
    }
  }
  #pragma unroll
  for (int t = 0; t < 4; ++t)
    #pragma unroll
    for (int r = 0; r < 4; ++r)
      C[(size_t)(m0 + l4 * 4 + r) * F + f0 + t * 16 + l15] = acc[t][r];
}

// ---- hgemmT: Vt[b][h][d][n] = (x @ v_w^T)^T   (A = v_w rows f, B = x rows bn)
__global__ __launch_bounds__(256) void hgemmT_v(const _Float16* __restrict__ W16,
                                                const _Float16* __restrict__ X16,
                                                _Float16* __restrict__ Vt) {
  const int tid = threadIdx.x, lane = tid & 63, wv = tid >> 6;
  const int l15 = lane & 15, l4 = lane >> 4;
  const int f0 = blockIdx.y * 64 + wv * 16;
  const int n0 = blockIdx.x * 64;
  f32x4 acc[4] = {{0,0,0,0},{0,0,0,0},{0,0,0,0},{0,0,0,0}};
  const _Float16* Ap = W16 + (size_t)(f0 + l15) * kE + l4 * 8;
  const _Float16* Bp = X16 + (size_t)(n0 + l15) * kE + l4 * 8;
  for (int k0 = 0; k0 < kE; k0 += 32) {
    const f16x8 af = *(const f16x8*)(Ap + k0);
    #pragma unroll
    for (int t = 0; t < 4; ++t) {
      const f16x8 bf = *(const f16x8*)(Bp + (size_t)t * 16 * kE + k0);
      acc[t] = __builtin_amdgcn_mfma_f32_16x16x32_f16(af, bf, acc[t], 0, 0, 0);
    }
  }
  #pragma unroll
  for (int t = 0; t < 4; ++t)
    #pragma unroll
    for (int r = 0; r < 4; ++r) {
      const int f  = f0 + l4 * 4 + r;
      const int ng = n0 + t * 16 + l15;
      const int bb = ng >> 9, n = ng & 511;
      Vt[(((size_t)((bb * kH + (f >> 6)) * kDV) + (f & 63)) * kN) + n] = (_Float16)acc[t][r];
    }
}

// ---- fused v2: ue-MFMA + exp + unnormalized PV-MFMA over a k-quarter -------
// grid (qt 32, kh 4, b 4) = 512 blocks (2/CU); 256 thr / 4 waves. Per 32-k tile:
// phase A: wave computes ue for its 8 k's (validated frag layout), exp, packs
//          f16 -> single P_lds buffer. __syncthreads().
// phase B: PV MFMA, A-frag = Vt global rows, B-frag = P_lds. __syncthreads().
// Textbook write/barrier/read/barrier — no cross-iteration LDS aliasing.
__global__ __launch_bounds__(256) void fused_attn2(
    const float* __restrict__ u, const int* __restrict__ umask,
    const float* __restrict__ uw, const float* __restrict__ ub,
    const _Float16* __restrict__ Vt,
    float* __restrict__ Opart, float* __restrict__ Spart) {
  __shared__ _Float16 P[16 * 648];
  __shared__ float S_lds[4][16][17];
  const int tid = threadIdx.x, lane = tid & 63, wv = tid >> 6;
  const int l15 = lane & 15, l4 = lane >> 4;
  const int qt = blockIdx.x, kh = blockIdx.y, b = blockIdx.z;
  const int q0 = qt * 16;
  const int kstart = kh * 128;

  f16x8 bfrag[2];
  #pragma unroll
  for (int ch = 0; ch < 2; ++ch) {
    const float* wp = uw + l15 * 64 + ch * 32 + l4 * 8;
    const float4 wa = *(const float4*)wp;
    const float4 wb = *(const float4*)(wp + 4);
    f16x8 bf;
    bf[0]=(_Float16)wa.x; bf[1]=(_Float16)wa.y; bf[2]=(_Float16)wa.z; bf[3]=(_Float16)wa.w;
    bf[4]=(_Float16)wb.x; bf[5]=(_Float16)wb.y; bf[6]=(_Float16)wb.z; bf[7]=(_Float16)wb.w;
    bfrag[ch] = bf;
  }
  const float bias = ub[l15];

  float s_acc[4] = {};
  f32x4 oacc[2][2][4];
  #pragma unroll
  for (int a = 0; a < 2; ++a)
    #pragma unroll
    for (int s = 0; s < 2; ++s)
      #pragma unroll
      for (int d = 0; d < 4; ++d) oacc[a][s][d] = (f32x4){0,0,0,0};

  for (int t = 0; t < 4; ++t) {
    const int k0 = kstart + t * 32;
    // ---- phase A: ue + exp for this wave's 8 k's ----
    _Float16 vals[4][8];
    #pragma unroll
    for (int kk = 0; kk < 8; ++kk) {
      const int k = k0 + wv * 8 + kk;
      const float* up = u + (((size_t)(b * kN + k)) * kN + q0 + l15) * kC + l4 * 8;
      f32x4 acc = {0.f, 0.f, 0.f, 0.f};
      #pragma unroll
      for (int ch = 0; ch < 2; ++ch) {
        const float4 a0 = *(const float4*)(up + ch * 32);
        const float4 a1 = *(const float4*)(up + ch * 32 + 4);
        f16x8 af;
        af[0]=(_Float16)a0.x; af[1]=(_Float16)a0.y; af[2]=(_Float16)a0.z; af[3]=(_Float16)a0.w;
        af[4]=(_Float16)a1.x; af[5]=(_Float16)a1.y; af[6]=(_Float16)a1.z; af[7]=(_Float16)a1.w;
        acc = __builtin_amdgcn_mfma_f32_16x16x32_f16(af, bfrag[ch], acc, 0, 0, 0);
      }
      const int* mrow = umask + (((size_t)(b * kN + k)) * kN + q0) * kH2 + l15;
      #pragma unroll
      for (int r = 0; r < 4; ++r) {
        const float e = mrow[(l4 * 4 + r) * kH2] ? 0.f : __expf(acc[r] + bias);
        s_acc[r] += e;
        vals[r][kk] = (_Float16)e;
      }
    }
    #pragma unroll
    for (int r = 0; r < 4; ++r) {
      union { _Float16 h[8]; int4 v; } PK;
      #pragma unroll
      for (int kk = 0; kk < 8; ++kk) PK.h[kk] = vals[r][kk];
      *(int4*)&P[l15 * 648 + (l4 * 4 + r) * 40 + wv * 8] = PK.v;
    }
    __syncthreads();  // all P writes visible
    // ---- phase B: PV via MFMA; wave handles heads wv*2, wv*2+1 ----
    #pragma unroll
    for (int hp = 0; hp < 2; ++hp) {
      const int h = wv * 2 + hp;
      f16x8 va[4];
      #pragma unroll
      for (int dt = 0; dt < 4; ++dt)
        va[dt] = *(const f16x8*)(Vt + (((size_t)((b * kH + h) * kDV + dt * 16 + l15)) * kN) + k0 + l4 * 8);
      #pragma unroll
      for (int s = 0; s < 2; ++s) {
        const int h2 = h * 2 + s;
        const f16x8 pb = *(const f16x8*)&P[h2 * 648 + l15 * 40 + l4 * 8];
        #pragma unroll
        for (int dt = 0; dt < 4; ++dt)
          oacc[hp][s][dt] = __builtin_amdgcn_mfma_f32_16x16x32_f16(va[dt], pb, oacc[hp][s][dt], 0, 0, 0);
      }
    }
    __syncthreads();  // all P reads done before next tile's writes
  }

  // ---- epilogue: reduce S across waves; write partials ----
  #pragma unroll
  for (int r = 0; r < 4; ++r) S_lds[wv][l15][l4 * 4 + r] = s_acc[r];
  __syncthreads();
  const int blk = (b * 4 + kh) * 32 + qt;
  {
    const int h2 = tid >> 4, q = tid & 15;
    const float S = S_lds[0][h2][q] + S_lds[1][h2][q] + S_lds[2][h2][q] + S_lds[3][h2][q];
    Spart[(size_t)blk * 256 + h2 * 16 + q] = S;
  }
  float* ob = Opart + (size_t)blk * (2 * 8 * 64 * 16);
  #pragma unroll
  for (int hp = 0; hp < 2; ++hp) {
    const int h = wv * 2 + hp;
    #pragma unroll
    for (int s = 0; s < 2; ++s)
      #pragma unroll
      for (int dt = 0; dt < 4; ++dt)
        #pragma unroll
        for (int r = 0; r < 4; ++r)
          ob[((s * 8 + h) * 64 + dt * 16 + l4 * 4 + r) * 16 + l15] = oacc[hp][s][dt][r];
  }
}

// ---- combine: O = O0/S0 - lam*O1/S1, LayerNorm, write a16 ------------------
// grid (qg 128, b 4); thread: h = tid>>5, d pair = (tid&31)*2; 4 q's per block.
__global__ __launch_bounds__(256) void combine_kernel(
    const float* __restrict__ Opart, const float* __restrict__ Spart,
    const float* __restrict__ lam_p, const float* __restrict__ ln_w,
    const float* __restrict__ ln_b, _Float16* __restrict__ a16) {
  const int tid = threadIdx.x;
  const int qg = blockIdx.x, b = blockIdx.y;
  const int h = tid >> 5, d0 = (tid & 31) * 2;
  const int qt = qg >> 2, qi0 = (qg & 3) * 4;
  const float lam = lam_p[0];
  size_t blk[4];
  #pragma unroll
  for (int j = 0; j < 4; ++j) blk[j] = (size_t)((b * 4 + j) * 32 + qt);

  float inv[2][4];
  #pragma unroll
  for (int s = 0; s < 2; ++s) {
    #pragma unroll
    for (int qp = 0; qp < 4; ++qp) {
      const int idx = (h * 2 + s) * 16 + qi0 + qp;
      float S = 0.f;
      #pragma unroll
      for (int j = 0; j < 4; ++j) S += Spart[blk[j] * 256 + idx];
      inv[s][qp] = (s ? lam : 1.0f) / S;
    }
  }
  float val[2][4];
  #pragma unroll
  for (int dd = 0; dd < 2; ++dd) {
    const int d = d0 + dd;
    const size_t off0 = ((size_t)(0 * 8 + h) * 64 + d) * 16 + qi0;
    const size_t off1 = ((size_t)(1 * 8 + h) * 64 + d) * 16 + qi0;
    f32x4 acc0 = {0,0,0,0}, acc1 = {0,0,0,0};
    #pragma unroll
    for (int j = 0; j < 4; ++j) {
      acc0 += *(const f32x4*)(Opart + blk[j] * 16384 + off0);
      acc1 += *(const f32x4*)(Opart + blk[j] * 16384 + off1);
    }
    #pragma unroll
    for (int qp = 0; qp < 4; ++qp)
      val[dd][qp] = acc0[qp] * inv[0][qp] - acc1[qp] * inv[1][qp];
  }
  // LayerNorm across d (64 values = 32 threads x 2), per (h, q')
  float s1[4], s2[4];
  #pragma unroll
  for (int qp = 0; qp < 4; ++qp) {
    s1[qp] = val[0][qp] + val[1][qp];
    s2[qp] = val[0][qp] * val[0][qp] + val[1][qp] * val[1][qp];
  }
  #pragma unroll
  for (int o = 1; o < 32; o <<= 1) {
    #pragma unroll
    for (int qp = 0; qp < 4; ++qp) {
      s1[qp] += __shfl_xor(s1[qp], o);
      s2[qp] += __shfl_xor(s2[qp], o);
    }
  }
  const float w0 = ln_w[d0], w1 = ln_w[d0 + 1];
  const float bb0 = ln_b[d0], bb1 = ln_b[d0 + 1];
  #pragma unroll
  for (int qp = 0; qp < 4; ++qp) {
    const float mu = s1[qp] * (1.0f / kDV);
    const float var = s2[qp] * (1.0f / kDV) - mu * mu;
    const float rstd = rsqrtf(var + 1e-5f);
    union { _Float16 hh[2]; uint uu; } PK;
    PK.hh[0] = (_Float16)((val[0][qp] - mu) * rstd * w0 + bb0);
    PK.hh[1] = (_Float16)((val[1][qp] - mu) * rstd * w1 + bb1);
    const int qglob = qt * 16 + qi0 + qp;
    *(uint*)(a16 + ((size_t)(b * kN + qglob)) * kE + h * kDV + d0) = PK.uu;
  }
}

// ----------------------------------------------------------------------------
extern "C" void kernel_launch(void* const* d_in, const int* in_sizes, int n_in,
                              void* d_out, int out_size, void* d_ws, size_t ws_size,
                              hipStream_t stream) {
  const float* x     = (const float*)d_in[0];
  const float* u     = (const float*)d_in[1];
  const int*   umask = (const int*)d_in[2];
  const float* v_w   = (const float*)d_in[3];
  const float* out_w = (const float*)d_in[4];
  const float* uw    = (const float*)d_in[5];
  const float* ubias = (const float*)d_in[6];
  const float* lq1   = (const float*)d_in[7];
  const float* lk1   = (const float*)d_in[8];
  const float* lq2   = (const float*)d_in[9];
  const float* lk2   = (const float*)d_in[10];
  const float* ln_w  = (const float*)d_in[11];
  const float* ln_b  = (const float*)d_in[12];
  float* out = (float*)d_out;

  char* ws = (char*)d_ws;
  const size_t sz_half = (size_t)kB * kN * kE * 2;             // 2 MB
  const size_t sz_w16  = (size_t)kE * kE * 2;                  // 512 KB
  const size_t sz_op   = (size_t)512 * 16384 * 4;              // 33.55 MB
  const size_t sz_sp   = (size_t)512 * 256 * 4;                // 512 KB
  const size_t off_x16 = 256;
  const size_t off_wv  = off_x16 + sz_half;
  const size_t off_wo  = off_wv + sz_w16;
  const size_t off_vt  = off_wo + sz_w16;
  const size_t off_a16 = off_vt + sz_half;
  const size_t off_op  = off_a16 + sz_half;
  const size_t off_sp  = off_op + sz_op;
  if (ws_size < off_sp + sz_sp) return;                        // ~41.3 MB
  float*    lam   = (float*)(ws);
  _Float16* x16   = (_Float16*)(ws + off_x16);
  _Float16* w16v  = (_Float16*)(ws + off_wv);
  _Float16* w16o  = (_Float16*)(ws + off_wo);
  _Float16* Vt    = (_Float16*)(ws + off_vt);
  _Float16* a16   = (_Float16*)(ws + off_a16);
  float*    Opart = (float*)(ws + off_op);
  float*    Spart = (float*)(ws + off_sp);

  prep_kernel<<<dim3(1537), dim3(256), 0, stream>>>(
      x, v_w, out_w, lq1, lk1, lq2, lk2, x16, w16v, w16o, lam);
  hgemmT_v<<<dim3(32, 8), dim3(256), 0, stream>>>(w16v, x16, Vt);
  fused_attn2<<<dim3(kN / 16, 4, kB), dim3(256), 0, stream>>>(
      u, umask, uw, ubias, Vt, Opart, Spart);
  combine_kernel<<<dim3(128, kB), dim3(256), 0, stream>>>(
      Opart, Spart, lam, ln_w, ln_b, a16);
  hgemm16f<<<dim3(kE / 64, (kB * kN) / 64), dim3(256), 0, stream>>>(
      a16, w16o, out, kB * kN, kE, kE);
}

// Round 7
// 119.817 us; speedup vs baseline: 1.2897x; 1.2897x over previous
//
#include <hip/hip_runtime.h>
#include <math.h>

typedef _Float16 f16x8 __attribute__((ext_vector_type(8)));
typedef _Float16 f16x4 __attribute__((ext_vector_type(4)));
typedef float    f32x4 __attribute__((ext_vector_type(4)));

constexpr int kB  = 4;
constexpr int kN  = 512;
constexpr int kE  = 512;
constexpr int kH  = 8;
constexpr int kH2 = 16;
constexpr int kC  = 64;
constexpr int kDV = 64;
constexpr float kLamInit = 0.2f;

// ---- prep: f32->f16 for x, v_w, out_w; block 1536 computes lambda ----------
__global__ __launch_bounds__(256) void prep_kernel(
    const float* __restrict__ x, const float* __restrict__ vw,
    const float* __restrict__ ow,
    const float* __restrict__ lq1, const float* __restrict__ lk1,
    const float* __restrict__ lq2, const float* __restrict__ lk2,
    _Float16* __restrict__ x16, _Float16* __restrict__ w16v,
    _Float16* __restrict__ w16o, float* __restrict__ lam_out) {
  const int bid = blockIdx.x;
  if (bid < 1536) {
    const float* src; _Float16* dst; int base;
    if (bid < 1024)      { src = x;  dst = x16;  base = bid; }
    else if (bid < 1280) { src = vw; dst = w16v; base = bid - 1024; }
    else                 { src = ow; dst = w16o; base = bid - 1280; }
    const int i = base * 256 + threadIdx.x;
    const float4 v = ((const float4*)src)[i];
    union { _Float16 h[4]; uint2 u2; } P;
    P.h[0]=(_Float16)v.x; P.h[1]=(_Float16)v.y;
    P.h[2]=(_Float16)v.z; P.h[3]=(_Float16)v.w;
    *(uint2*)(dst + i * 4) = P.u2;
  } else if (threadIdx.x < 64) {
    float s1 = 0.f, s2 = 0.f;
    for (int i = threadIdx.x; i < kE; i += 64) { s1 += lq1[i]*lk1[i]; s2 += lq2[i]*lk2[i]; }
    #pragma unroll
    for (int o = 32; o; o >>= 1) { s1 += __shfl_xor(s1, o); s2 += __shfl_xor(s2, o); }
    if (threadIdx.x == 0) lam_out[0] = expf(s1) - expf(s2) + kLamInit;
  }
}

// ---- hgemm: C[M,F] = A16[M,K] x W16[F,K]^T (f32 out) -----------------------
__global__ __launch_bounds__(256) void hgemm16f(const _Float16* __restrict__ A16,
                                                const _Float16* __restrict__ W16,
                                                float* __restrict__ C,
                                                int M, int F, int K) {
  const int tid = threadIdx.x, lane = tid & 63, wv = tid >> 6;
  const int l15 = lane & 15, l4 = lane >> 4;
  const int m0 = blockIdx.y * 64 + wv * 16;
  const int f0 = blockIdx.x * 64;
  f32x4 acc[4] = {{0,0,0,0},{0,0,0,0},{0,0,0,0},{0,0,0,0}};
  const _Float16* Ap = A16 + (size_t)(m0 + l15) * K + l4 * 8;
  const _Float16* Wp = W16 + (size_t)(f0 + l15) * K + l4 * 8;
  for (int k0 = 0; k0 < K; k0 += 32) {
    const f16x8 af = *(const f16x8*)(Ap + k0);
    #pragma unroll
    for (int t = 0; t < 4; ++t) {
      const f16x8 bf = *(const f16x8*)(Wp + (size_t)t * 16 * K + k0);
      acc[t] = __builtin_amdgcn_mfma_f32_16x16x32_f16(af, bf, acc[t], 0, 0, 0);
    }
  }
  #pragma unroll
  for (int t = 0; t < 4; ++t)
    #pragma unroll
    for (int r = 0; r < 4; ++r)
      C[(size_t)(m0 + l4 * 4 + r) * F + f0 + t * 16 + l15] = acc[t][r];
}

// ---- hgemmT: Vt[b][h][d][n] = (x @ v_w^T)^T --------------------------------
__global__ __launch_bounds__(256) void hgemmT_v(const _Float16* __restrict__ W16,
                                                const _Float16* __restrict__ X16,
                                                _Float16* __restrict__ Vt) {
  const int tid = threadIdx.x, lane = tid & 63, wv = tid >> 6;
  const int l15 = lane & 15, l4 = lane >> 4;
  const int f0 = blockIdx.y * 64 + wv * 16;
  const int n0 = blockIdx.x * 64;
  f32x4 acc[4] = {{0,0,0,0},{0,0,0,0},{0,0,0,0},{0,0,0,0}};
  const _Float16* Ap = W16 + (size_t)(f0 + l15) * kE + l4 * 8;
  const _Float16* Bp = X16 + (size_t)(n0 + l15) * kE + l4 * 8;
  for (int k0 = 0; k0 < kE; k0 += 32) {
    const f16x8 af = *(const f16x8*)(Ap + k0);
    #pragma unroll
    for (int t = 0; t < 4; ++t) {
      const f16x8 bf = *(const f16x8*)(Bp + (size_t)t * 16 * kE + k0);
      acc[t] = __builtin_amdgcn_mfma_f32_16x16x32_f16(af, bf, acc[t], 0, 0, 0);
    }
  }
  #pragma unroll
  for (int t = 0; t < 4; ++t)
    #pragma unroll
    for (int r = 0; r < 4; ++r) {
      const int f  = f0 + l4 * 4 + r;
      const int ng = n0 + t * 16 + l15;
      const int bb = ng >> 9, n = ng & 511;
      Vt[(((size_t)((bb * kH + (f >> 6)) * kDV) + (f & 63)) * kN) + n] = (_Float16)acc[t][r];
    }
}

// ---- fused v4: 8 waves (wave = 1 head), kh=4, 16 waves/CU ------------------
// grid (qt 32, kh 4, b 4) = 512 blocks x 512 thr. Per 32-k tile:
// phase A: wave computes ue for its 4 k's (k = k0 + wv*4 + kk), exp, packs
//          f16 -> P_lds. barrier.
// phase B: wave's head h = wv: A-frag = Vt rows, B-frag = P_lds. barrier.
__global__ __launch_bounds__(512, 4) void fused_attn4(
    const float* __restrict__ u, const int* __restrict__ umask,
    const float* __restrict__ uw, const float* __restrict__ ub,
    const _Float16* __restrict__ Vt,
    _Float16* __restrict__ Opart, float* __restrict__ Spart) {
  __shared__ _Float16 P[16 * 648];
  __shared__ float S_lds[8][16][17];
  const int tid = threadIdx.x, lane = tid & 63, wv = tid >> 6;  // wv 0..7
  const int l15 = lane & 15, l4 = lane >> 4;
  const int qt = blockIdx.x, kh = blockIdx.y, b = blockIdx.z;
  const int q0 = qt * 16;
  const int kstart = kh * 128;

  f16x8 bfrag[2];
  #pragma unroll
  for (int ch = 0; ch < 2; ++ch) {
    const float* wp = uw + l15 * 64 + ch * 32 + l4 * 8;
    const float4 wa = *(const float4*)wp;
    const float4 wb = *(const float4*)(wp + 4);
    f16x8 bf;
    bf[0]=(_Float16)wa.x; bf[1]=(_Float16)wa.y; bf[2]=(_Float16)wa.z; bf[3]=(_Float16)wa.w;
    bf[4]=(_Float16)wb.x; bf[5]=(_Float16)wb.y; bf[6]=(_Float16)wb.z; bf[7]=(_Float16)wb.w;
    bfrag[ch] = bf;
  }
  const float bias = ub[l15];

  float s_acc[4] = {};
  f32x4 oacc[2][4];
  #pragma unroll
  for (int s = 0; s < 2; ++s)
    #pragma unroll
    for (int d = 0; d < 4; ++d) oacc[s][d] = (f32x4){0,0,0,0};

  for (int t = 0; t < 4; ++t) {
    const int k0 = kstart + t * 32;
    // ---- phase A: ue + exp for this wave's 4 k's ----
    _Float16 vals[4][4];
    #pragma unroll
    for (int kk = 0; kk < 4; ++kk) {
      const int k = k0 + wv * 4 + kk;
      const float* up = u + (((size_t)(b * kN + k)) * kN + q0 + l15) * kC + l4 * 8;
      f32x4 acc = {0.f, 0.f, 0.f, 0.f};
      #pragma unroll
      for (int ch = 0; ch < 2; ++ch) {
        const float4 a0 = *(const float4*)(up + ch * 32);
        const float4 a1 = *(const float4*)(up + ch * 32 + 4);
        f16x8 af;
        af[0]=(_Float16)a0.x; af[1]=(_Float16)a0.y; af[2]=(_Float16)a0.z; af[3]=(_Float16)a0.w;
        af[4]=(_Float16)a1.x; af[5]=(_Float16)a1.y; af[6]=(_Float16)a1.z; af[7]=(_Float16)a1.w;
        acc = __builtin_amdgcn_mfma_f32_16x16x32_f16(af, bfrag[ch], acc, 0, 0, 0);
      }
      const int* mrow = umask + (((size_t)(b * kN + k)) * kN + q0) * kH2 + l15;
      #pragma unroll
      for (int r = 0; r < 4; ++r) {
        const float e = mrow[(l4 * 4 + r) * kH2] ? 0.f : __expf(acc[r] + bias);
        s_acc[r] += e;
        vals[r][kk] = (_Float16)e;
      }
    }
    #pragma unroll
    for (int r = 0; r < 4; ++r) {
      union { _Float16 h[4]; uint2 u2; } PK;
      #pragma unroll
      for (int kk = 0; kk < 4; ++kk) PK.h[kk] = vals[r][kk];
      *(uint2*)&P[l15 * 648 + (l4 * 4 + r) * 40 + wv * 4] = PK.u2;
    }
    __syncthreads();  // all P writes visible
    // ---- phase B: PV via MFMA; wave's head h = wv ----
    f16x8 va[4];
    #pragma unroll
    for (int dt = 0; dt < 4; ++dt)
      va[dt] = *(const f16x8*)(Vt + (((size_t)((b * kH + wv) * kDV + dt * 16 + l15)) * kN) + k0 + l4 * 8);
    #pragma unroll
    for (int s = 0; s < 2; ++s) {
      const f16x8 pb = *(const f16x8*)&P[(wv * 2 + s) * 648 + l15 * 40 + l4 * 8];
      #pragma unroll
      for (int dt = 0; dt < 4; ++dt)
        oacc[s][dt] = __builtin_amdgcn_mfma_f32_16x16x32_f16(va[dt], pb, oacc[s][dt], 0, 0, 0);
    }
    __syncthreads();  // all P reads done before next tile's writes
  }

  // ---- epilogue ----
  #pragma unroll
  for (int r = 0; r < 4; ++r) S_lds[wv][l15][l4 * 4 + r] = s_acc[r];
  __syncthreads();
  const int blk = (b * 4 + kh) * 32 + qt;
  if (tid < 256) {
    const int h2 = tid >> 4, q = tid & 15;
    float S = 0.f;
    #pragma unroll
    for (int j = 0; j < 8; ++j) S += S_lds[j][h2][q];
    Spart[(size_t)blk * 256 + h2 * 16 + q] = S;
  }
  _Float16* ob = Opart + (size_t)blk * 16384;
  #pragma unroll
  for (int s = 0; s < 2; ++s)
    #pragma unroll
    for (int dt = 0; dt < 4; ++dt)
      #pragma unroll
      for (int r = 0; r < 4; ++r)
        ob[((size_t)(s * 8 + wv) * 64 + dt * 16 + l4 * 4 + r) * 16 + l15] =
            (_Float16)oacc[s][dt][r];
}

// ---- combine3: coalesced; grid (qt 32, h 8, b 4), 256 thr ------------------
// thread reads flat f16x4 at tid*4 (d = tid>>2, q-quad = (tid&3)*4); sums 4 kh
// parts; val = A0*inv0 - A1*inv1; LN via LDS [64][17] + 16-lane shuffle.
__global__ __launch_bounds__(256) void combine3(
    const _Float16* __restrict__ Opart, const float* __restrict__ Spart,
    const float* __restrict__ lam_p, const float* __restrict__ ln_w,
    const float* __restrict__ ln_b, _Float16* __restrict__ a16) {
  __shared__ float vsh[64][17];
  __shared__ float inv_sh[2][16];
  const int tid = threadIdx.x;
  const int qt = blockIdx.x, h = blockIdx.y, b = blockIdx.z;
  if (tid < 32) {
    const int s = tid >> 4, q = tid & 15;
    float S = 0.f;
    #pragma unroll
    for (int kh = 0; kh < 4; ++kh)
      S += Spart[(size_t)((b * 4 + kh) * 32 + qt) * 256 + (h * 2 + s) * 16 + q];
    inv_sh[s][q] = (s ? lam_p[0] : 1.0f) / S;
  }
  float a0[4] = {}, a1[4] = {};
  #pragma unroll
  for (int kh = 0; kh < 4; ++kh) {
    const size_t base = (size_t)((b * 4 + kh) * 32 + qt) * 16384;
    const f16x4 p0 = *(const f16x4*)(Opart + base + (size_t)(0 * 8 + h) * 1024 + tid * 4);
    const f16x4 p1 = *(const f16x4*)(Opart + base + (size_t)(1 * 8 + h) * 1024 + tid * 4);
    #pragma unroll
    for (int j = 0; j < 4; ++j) { a0[j] += (float)p0[j]; a1[j] += (float)p1[j]; }
  }
  __syncthreads();  // inv_sh ready
  {
    const int d = tid >> 2, q0i = (tid & 3) * 4;
    #pragma unroll
    for (int j = 0; j < 4; ++j)
      vsh[d][q0i + j] = a0[j] * inv_sh[0][q0i + j] - a1[j] * inv_sh[1][q0i + j];
  }
  __syncthreads();
  // LN: thread (q = tid>>4, i = tid&15); 16 threads cover 64 d per q
  const int q = tid >> 4, i = tid & 15;
  float vv[4], s1 = 0.f, s2 = 0.f;
  #pragma unroll
  for (int jj = 0; jj < 4; ++jj) {
    vv[jj] = vsh[i * 4 + jj][q];
    s1 += vv[jj]; s2 += vv[jj] * vv[jj];
  }
  #pragma unroll
  for (int o = 1; o < 16; o <<= 1) { s1 += __shfl_xor(s1, o); s2 += __shfl_xor(s2, o); }
  const float mu = s1 * (1.0f / kDV);
  const float var = s2 * (1.0f / kDV) - mu * mu;
  const float rstd = rsqrtf(var + 1e-5f);
  union { _Float16 hh[4]; uint2 u2; } PK;
  #pragma unroll
  for (int jj = 0; jj < 4; ++jj)
    PK.hh[jj] = (_Float16)((vv[jj] - mu) * rstd * ln_w[i * 4 + jj] + ln_b[i * 4 + jj]);
  *(uint2*)(a16 + ((size_t)(b * kN + qt * 16 + q)) * kE + h * kDV + i * 4) = PK.u2;
}

// ----------------------------------------------------------------------------
extern "C" void kernel_launch(void* const* d_in, const int* in_sizes, int n_in,
                              void* d_out, int out_size, void* d_ws, size_t ws_size,
                              hipStream_t stream) {
  const float* x     = (const float*)d_in[0];
  const float* u     = (const float*)d_in[1];
  const int*   umask = (const int*)d_in[2];
  const float* v_w   = (const float*)d_in[3];
  const float* out_w = (const float*)d_in[4];
  const float* uw    = (const float*)d_in[5];
  const float* ubias = (const float*)d_in[6];
  const float* lq1   = (const float*)d_in[7];
  const float* lk1   = (const float*)d_in[8];
  const float* lq2   = (const float*)d_in[9];
  const float* lk2   = (const float*)d_in[10];
  const float* ln_w  = (const float*)d_in[11];
  const float* ln_b  = (const float*)d_in[12];
  float* out = (float*)d_out;

  char* ws = (char*)d_ws;
  const size_t sz_half = (size_t)kB * kN * kE * 2;             // 2 MB
  const size_t sz_w16  = (size_t)kE * kE * 2;                  // 512 KB
  const size_t sz_op   = (size_t)512 * 16384 * 2;              // 16.78 MB (f16)
  const size_t sz_sp   = (size_t)512 * 256 * 4;                // 512 KB
  const size_t off_x16 = 256;
  const size_t off_wv  = off_x16 + sz_half;
  const size_t off_wo  = off_wv + sz_w16;
  const size_t off_vt  = off_wo + sz_w16;
  const size_t off_a16 = off_vt + sz_half;
  const size_t off_op  = off_a16 + sz_half;
  const size_t off_sp  = off_op + sz_op;
  if (ws_size < off_sp + sz_sp) return;                        // ~24.6 MB
  float*    lam   = (float*)(ws);
  _Float16* x16   = (_Float16*)(ws + off_x16);
  _Float16* w16v  = (_Float16*)(ws + off_wv);
  _Float16* w16o  = (_Float16*)(ws + off_wo);
  _Float16* Vt    = (_Float16*)(ws + off_vt);
  _Float16* a16   = (_Float16*)(ws + off_a16);
  _Float16* Opart = (_Float16*)(ws + off_op);
  float*    Spart = (float*)(ws + off_sp);

  prep_kernel<<<dim3(1537), dim3(256), 0, stream>>>(
      x, v_w, out_w, lq1, lk1, lq2, lk2, x16, w16v, w16o, lam);
  hgemmT_v<<<dim3(32, 8), dim3(256), 0, stream>>>(w16v, x16, Vt);
  fused_attn4<<<dim3(kN / 16, 4, kB), dim3(512), 0, stream>>>(
      u, umask, uw, ubias, Vt, Opart, Spart);
  combine3<<<dim3(kN / 16, kH, kB), dim3(256), 0, stream>>>(
      Opart, Spart, lam, ln_w, ln_b, a16);
  hgemm16f<<<dim3(kE / 64, (kB * kN) / 64), dim3(256), 0, stream>>>(
      a16, w16o, out, kB * kN, kE, kE);
}